// Round 2
// baseline (964.540 us; speedup 1.0000x reference)
//
#include <hip/hip_runtime.h>

// ---------------------------------------------------------------------------
// SparseConvResBlock fp32 baseline (v2: workspace fits in 192 MiB + 96 KiB).
//   B=16, C=256, H=W=64 (HW=4096, M=65536 tokens), SKIP=256, TE=1024, ZD=256,
//   K=7, MULT=2.
//
// Kernel graph (stream-ordered):
//   K0 modvecs   : t/z per-batch FiLM vectors -> vecs[6][16][256]
//   K1 skipgemm  : [M,512]@[512,256]+bias -> xt ; fused LN1+FiLM -> hf
//   K2 conv      : 7x7 depthwise(hf)/norm + xt -> xt2   (IN-PLACE over xt)
//   K3 mod2      : LN2+FiLM(xt2) -> hmod (reuses hf region)
//   K4 mlp1      : gelu(hmod@w1+b1) -> mid  (bf16)
//   K5 mlp2      : mid@w2+b2 + xt2 -> out (NCHW transposed store via LDS)
//
// ws layout (bytes):
//   [0,64Mi)    xt  -> xt2 (fp32 [M,256], conv writes in place)
//   [64,128Mi)  hf  -> hmod (fp32 [M,256])
//   [128,192Mi) mid (bf16 [M,512])
//   [192Mi,+96Ki) vecs (fp32 6*16*256)
// ---------------------------------------------------------------------------

#define REG_BYTES ((size_t)1 << 26)   // 64 MiB = one [M,256] fp32 region

__device__ __forceinline__ float gelu_f(float x) {
    return 0.5f * x * (1.0f + erff(x * 0.70710678118654752f));
}

__device__ __forceinline__ unsigned short f2bf(float f) {
    unsigned int u = __float_as_uint(f);
    unsigned int r = (u + 0x7FFFu + ((u >> 16) & 1u)) >> 16;
    return (unsigned short)r;
}

__device__ __forceinline__ void fma64(float acc[4][16], const float4 av,
                                      const float4 b0, const float4 b1,
                                      const float4 b2, const float4 b3) {
    const float a[4] = {av.x, av.y, av.z, av.w};
    const float4 bs[4] = {b0, b1, b2, b3};
#pragma unroll
    for (int ri = 0; ri < 4; ++ri) {
#pragma unroll
        for (int cc = 0; cc < 4; ++cc) {
            acc[ri][cc * 4 + 0] = fmaf(a[ri], bs[cc].x, acc[ri][cc * 4 + 0]);
            acc[ri][cc * 4 + 1] = fmaf(a[ri], bs[cc].y, acc[ri][cc * 4 + 1]);
            acc[ri][cc * 4 + 2] = fmaf(a[ri], bs[cc].z, acc[ri][cc * 4 + 2]);
            acc[ri][cc * 4 + 3] = fmaf(a[ri], bs[cc].w, acc[ri][cc * 4 + 3]);
        }
    }
}

// --------------------------- K0: FiLM vectors ------------------------------
// grid (6, 16), block 256.  vecs slots: 0=t1s 1=t1b 2=t2s 3=t2b 4=zs1 5=zs2
__global__ void k0_modvecs(const float* __restrict__ t, const float* __restrict__ z,
                           const float* __restrict__ tm1_w, const float* __restrict__ tm1_b,
                           const float* __restrict__ tm2_w, const float* __restrict__ tm2_b,
                           const float* __restrict__ zm1_w1, const float* __restrict__ zm1_b1,
                           const float* __restrict__ zm1_w2, const float* __restrict__ zm1_b2,
                           const float* __restrict__ zm2_w1, const float* __restrict__ zm2_b1,
                           const float* __restrict__ zm2_w2, const float* __restrict__ zm2_b2,
                           float* __restrict__ vecs) {
    const int unit = blockIdx.x;
    const int b = blockIdx.y;
    const int tid = threadIdx.x;
    __shared__ float sb[1024];
    if (unit < 4) {
        const float* tw = (unit < 2) ? tm1_w : tm2_w;
        const float* tb = (unit < 2) ? tm1_b : tm2_b;
        for (int i = tid; i < 1024; i += 256) sb[i] = gelu_f(t[b * 1024 + i]);
        __syncthreads();
        const int half = unit & 1;           // 0: scale (cols 0..255), 1: shift
        const int n = half * 256 + tid;
        float acc = tb[n];
#pragma unroll 8
        for (int k = 0; k < 1024; ++k) acc = fmaf(sb[k], tw[k * 512 + n], acc);
        const int slot = (unit < 2) ? half : (2 + half);
        vecs[(slot * 16 + b) * 256 + tid] = acc;
    } else {
        const float* w1 = (unit == 4) ? zm1_w1 : zm2_w1;
        const float* b1 = (unit == 4) ? zm1_b1 : zm2_b1;
        const float* w2 = (unit == 4) ? zm1_w2 : zm2_w2;
        const float* b2 = (unit == 4) ? zm1_b2 : zm2_b2;
        sb[tid] = z[b * 256 + tid];
        __syncthreads();
        float acc = b1[tid];
#pragma unroll 8
        for (int k = 0; k < 256; ++k) acc = fmaf(sb[k], w1[k * 256 + tid], acc);
        sb[256 + tid] = gelu_f(acc);
        __syncthreads();
        float acc2 = b2[tid];
#pragma unroll 8
        for (int k = 0; k < 256; ++k) acc2 = fmaf(sb[256 + k], w2[k * 256 + tid], acc2);
        vecs[((unit) * 16 + b) * 256 + tid] = acc2;   // unit 4->zs1, 5->zs2
    }
}

// ------------------- K1: skip_linear GEMM + LN1 + FiLM ---------------------
// grid 1024, block 256. M-tile 64, N=256 full, K=512 (k<256: x, else skip).
__global__ __launch_bounds__(256, 2)
void k1_skipgemm(const float* __restrict__ x, const float* __restrict__ skip,
                 const float* __restrict__ skip_w, const float* __restrict__ skip_b,
                 const float* __restrict__ ln_g, const float* __restrict__ ln_b,
                 const float* __restrict__ vecs,
                 float* __restrict__ xt, float* __restrict__ hf) {
    __shared__ float As[32][72];     // A^T tile: As[k][m]
    __shared__ float Bs[32][260];
    const int tid = threadIdx.x;
    const int m0 = blockIdx.x * 64;
    const int b = m0 >> 12;
    const int s0 = m0 & 4095;
    const int ty = tid >> 4, tx = tid & 15;
    const int ka = tid >> 3, qa = tid & 7;

    float acc[4][16];
#pragma unroll
    for (int i = 0; i < 4; ++i)
#pragma unroll
        for (int j = 0; j < 16; ++j) acc[i][j] = 0.f;

    const float* xb = x + (size_t)b * 1048576 + s0;
    const float* kb_ = skip + (size_t)b * 1048576 + s0;

    for (int kt = 0; kt < 16; ++kt) {
        const int k0 = kt * 32;
        const int kg = k0 + ka;
        const float* colp = (kg < 256) ? (xb + (size_t)kg * 4096)
                                       : (kb_ + (size_t)(kg - 256) * 4096);
        float4 a0 = ((const float4*)colp)[qa];
        float4 a1 = ((const float4*)colp)[qa + 8];
        *(float4*)&As[ka][qa * 4] = a0;
        *(float4*)&As[ka][qa * 4 + 32] = a1;
#pragma unroll
        for (int r = 0; r < 8; ++r) {
            const int qd = qa + r * 8;
            *(float4*)&Bs[ka][qd * 4] =
                *(const float4*)&skip_w[(size_t)(k0 + ka) * 256 + qd * 4];
        }
        __syncthreads();
#pragma unroll 8
        for (int kk = 0; kk < 32; ++kk) {
            float4 av = *(const float4*)&As[kk][ty * 4];
            float4 b0 = *(const float4*)&Bs[kk][tx * 4];
            float4 b1 = *(const float4*)&Bs[kk][64 + tx * 4];
            float4 b2 = *(const float4*)&Bs[kk][128 + tx * 4];
            float4 b3 = *(const float4*)&Bs[kk][192 + tx * 4];
            fma64(acc, av, b0, b1, b2, b3);
        }
        __syncthreads();
    }

    // epilogue: +bias, write xt, LN stats
    float s1[4] = {0, 0, 0, 0}, s2[4] = {0, 0, 0, 0};
#pragma unroll
    for (int cc = 0; cc < 4; ++cc) {
        float4 bias = *(const float4*)&skip_b[cc * 64 + tx * 4];
#pragma unroll
        for (int ri = 0; ri < 4; ++ri) {
            float v0 = acc[ri][cc * 4 + 0] + bias.x;
            float v1 = acc[ri][cc * 4 + 1] + bias.y;
            float v2 = acc[ri][cc * 4 + 2] + bias.z;
            float v3 = acc[ri][cc * 4 + 3] + bias.w;
            acc[ri][cc * 4 + 0] = v0; acc[ri][cc * 4 + 1] = v1;
            acc[ri][cc * 4 + 2] = v2; acc[ri][cc * 4 + 3] = v3;
            *(float4*)&xt[(size_t)(m0 + ty * 4 + ri) * 256 + cc * 64 + tx * 4] =
                make_float4(v0, v1, v2, v3);
            s1[ri] += v0 + v1 + v2 + v3;
            s2[ri] += v0 * v0 + v1 * v1 + v2 * v2 + v3 * v3;
        }
    }
#pragma unroll
    for (int ri = 0; ri < 4; ++ri) {
#pragma unroll
        for (int msk = 1; msk < 16; msk <<= 1) {
            s1[ri] += __shfl_xor(s1[ri], msk);
            s2[ri] += __shfl_xor(s2[ri], msk);
        }
    }
    float mean[4], rstd[4];
#pragma unroll
    for (int ri = 0; ri < 4; ++ri) {
        mean[ri] = s1[ri] * (1.f / 256.f);
        float var = s2[ri] * (1.f / 256.f) - mean[ri] * mean[ri];
        rstd[ri] = rsqrtf(var + 1e-5f);
    }
    const float* t1s = vecs + (0 * 16 + b) * 256;
    const float* t1b = vecs + (1 * 16 + b) * 256;
    const float* zs1 = vecs + (4 * 16 + b) * 256;
#pragma unroll
    for (int cc = 0; cc < 4; ++cc) {
        const int col = cc * 64 + tx * 4;
        float4 g = *(const float4*)&ln_g[col];
        float4 bb = *(const float4*)&ln_b[col];
        float4 ts = *(const float4*)&t1s[col];
        float4 th = *(const float4*)&t1b[col];
        float4 zz = *(const float4*)&zs1[col];
#pragma unroll
        for (int ri = 0; ri < 4; ++ri) {
            float h0 = (acc[ri][cc * 4 + 0] - mean[ri]) * rstd[ri] * g.x + bb.x;
            float h1 = (acc[ri][cc * 4 + 1] - mean[ri]) * rstd[ri] * g.y + bb.y;
            float h2 = (acc[ri][cc * 4 + 2] - mean[ri]) * rstd[ri] * g.z + bb.z;
            float h3 = (acc[ri][cc * 4 + 3] - mean[ri]) * rstd[ri] * g.w + bb.w;
            h0 = (h0 * (1.f + ts.x) + th.x) * (1.f + zz.x);
            h1 = (h1 * (1.f + ts.y) + th.y) * (1.f + zz.y);
            h2 = (h2 * (1.f + ts.z) + th.z) * (1.f + zz.z);
            h3 = (h3 * (1.f + ts.w) + th.w) * (1.f + zz.w);
            *(float4*)&hf[(size_t)(m0 + ty * 4 + ri) * 256 + col] =
                make_float4(h0, h1, h2, h3);
        }
    }
}

// -------------------- K2: depthwise 7x7 conv + residual --------------------
// grid 4096 = b(16) x tile(16: 4x4 of 16x16 px) x cg(16: 16 ch).  block 256.
// Residual is IN PLACE: reads xtio[g], writes conv+residual back to xtio[g]
// from the same thread in the same iteration.
__global__ __launch_bounds__(256, 2)
void k2_conv(const float* __restrict__ hf, float* __restrict__ xtio,
             const float* __restrict__ conv_k, const float* __restrict__ norm) {
    __shared__ float in_t[16 * 616];   // [c][yy 22][xx stride 28]
    __shared__ float wk[16 * 49];
    const int bid = blockIdx.x;
    const int cg = bid & 15;
    const int tile = (bid >> 4) & 15;
    const int b = bid >> 8;
    const int y0 = (tile >> 2) * 16, x0 = (tile & 3) * 16;
    const int c0 = cg * 16;
    const int tid = threadIdx.x;

    // stage 22x22 halo x 16 ch
    for (int it = 0; it < 8; ++it) {
        const int idx = it * 256 + tid;
        if (idx < 1936) {
            const int c4 = idx & 3, px = idx >> 2;
            const int yy = px / 22, xx = px - yy * 22;
            const int gy = y0 + yy - 3, gx = x0 + xx - 3;
            float4 v = make_float4(0.f, 0.f, 0.f, 0.f);
            if ((unsigned)gy < 64u && (unsigned)gx < 64u)
                v = *(const float4*)&hf[((size_t)(b * 4096 + gy * 64 + gx)) * 256 + c0 + c4 * 4];
            const int base = (c4 * 4) * 616 + yy * 28 + xx;
            in_t[base] = v.x; in_t[base + 616] = v.y;
            in_t[base + 1232] = v.z; in_t[base + 1848] = v.w;
        }
    }
    for (int idx = tid; idx < 784; idx += 256) wk[idx] = conv_k[c0 * 49 + idx];
    __syncthreads();

    const int c = tid >> 4, yy = tid & 15;
    float w[49];
#pragma unroll
    for (int i = 0; i < 49; ++i) w[i] = wk[c * 49 + i];
    float acc[16];
#pragma unroll
    for (int i = 0; i < 16; ++i) acc[i] = 0.f;
    const float* rowbase = &in_t[c * 616];
#pragma unroll
    for (int ky = 0; ky < 7; ++ky) {
        float r[24];
#pragma unroll
        for (int q = 0; q < 6; ++q)
            *(float4*)&r[q * 4] = *(const float4*)&rowbase[(yy + ky) * 28 + q * 4];
#pragma unroll
        for (int kx = 0; kx < 7; ++kx) {
            const float wv = w[ky * 7 + kx];
#pragma unroll
            for (int xo = 0; xo < 16; ++xo)
                acc[xo] = fmaf(wv, r[xo + kx], acc[xo]);
        }
    }
    float nr[16];
#pragma unroll
    for (int q = 0; q < 4; ++q)
        *(float4*)&nr[q * 4] = *(const float4*)&norm[(y0 + yy) * 64 + x0 + q * 4];
#pragma unroll
    for (int xo = 0; xo < 16; ++xo) acc[xo] = acc[xo] / nr[xo];

    // stage transposed for coalesced NHWC write, reuse in_t
    __syncthreads();
    float* out_t = in_t;               // [px 256][17]
#pragma unroll
    for (int xo = 0; xo < 16; ++xo)
        out_t[(yy * 16 + xo) * 17 + c] = acc[xo];
    __syncthreads();
    for (int it = 0; it < 4; ++it) {
        const int idx = it * 256 + tid;
        const int c4 = idx & 3, px = idx >> 2;
        const int lb = px * 17 + c4 * 4;
        float4 v = make_float4(out_t[lb], out_t[lb + 1], out_t[lb + 2], out_t[lb + 3]);
        const size_t g = ((size_t)(b * 4096 + (y0 + (px >> 4)) * 64 + x0 + (px & 15))) * 256
                         + c0 + c4 * 4;
        float4 xv = *(const float4*)&xtio[g];
        v.x += xv.x; v.y += xv.y; v.z += xv.z; v.w += xv.w;
        *(float4*)&xtio[g] = v;
    }
}

// ------------------------- K3: LN2 + FiLM (mod2) ---------------------------
// grid 16384, block 256 (4 waves = 4 tokens).
__global__ void k3_mod2(const float* __restrict__ xt2,
                        const float* __restrict__ ln_g, const float* __restrict__ ln_b,
                        const float* __restrict__ vecs, float* __restrict__ hmod) {
    const int tid = threadIdx.x;
    const int wid = tid >> 6, lane = tid & 63;
    const int token = blockIdx.x * 4 + wid;
    const int b = token >> 12;
    const float4 v = *(const float4*)&xt2[(size_t)token * 256 + lane * 4];
    float s1 = v.x + v.y + v.z + v.w;
    float s2 = v.x * v.x + v.y * v.y + v.z * v.z + v.w * v.w;
#pragma unroll
    for (int m = 1; m < 64; m <<= 1) {
        s1 += __shfl_xor(s1, m);
        s2 += __shfl_xor(s2, m);
    }
    const float mean = s1 * (1.f / 256.f);
    const float var = s2 * (1.f / 256.f) - mean * mean;
    const float rstd = rsqrtf(var + 1e-5f);
    const int col = lane * 4;
    float4 g = *(const float4*)&ln_g[col];
    float4 bb = *(const float4*)&ln_b[col];
    float4 ts = *(const float4*)&vecs[(2 * 16 + b) * 256 + col];
    float4 th = *(const float4*)&vecs[(3 * 16 + b) * 256 + col];
    float4 zz = *(const float4*)&vecs[(5 * 16 + b) * 256 + col];
    float h0 = (v.x - mean) * rstd * g.x + bb.x;
    float h1 = (v.y - mean) * rstd * g.y + bb.y;
    float h2 = (v.z - mean) * rstd * g.z + bb.z;
    float h3 = (v.w - mean) * rstd * g.w + bb.w;
    h0 = (h0 * (1.f + ts.x) + th.x) * (1.f + zz.x);
    h1 = (h1 * (1.f + ts.y) + th.y) * (1.f + zz.y);
    h2 = (h2 * (1.f + ts.z) + th.z) * (1.f + zz.z);
    h3 = (h3 * (1.f + ts.w) + th.w) * (1.f + zz.w);
    *(float4*)&hmod[(size_t)token * 256 + col] = make_float4(h0, h1, h2, h3);
}

// ------------------------ K4: MLP GEMM1 + gelu -----------------------------
// grid (1024, 2), block 256.  M-tile 64, N-tile 256 (of 512), K=256.
// Output `mid` stored as bf16 (raw u16).
__global__ __launch_bounds__(256, 2)
void k4_mlp1(const float* __restrict__ A, const float* __restrict__ w1,
             const float* __restrict__ b1, unsigned short* __restrict__ mid) {
    __shared__ float As[32][68];
    __shared__ float Bs[32][260];
    const int tid = threadIdx.x;
    const int m0 = blockIdx.x * 64;
    const int n0 = blockIdx.y * 256;
    const int ty = tid >> 4, tx = tid & 15;
    const int ia = tid >> 2, qa = tid & 3;
    const int kb = tid >> 3, qb = tid & 7;

    float acc[4][16];
#pragma unroll
    for (int i = 0; i < 4; ++i)
#pragma unroll
        for (int j = 0; j < 16; ++j) acc[i][j] = 0.f;

    for (int kt = 0; kt < 8; ++kt) {
        const int k0 = kt * 32;
        float4 a0 = *(const float4*)&A[(size_t)(m0 + ia) * 256 + k0 + qa * 4];
        float4 a1 = *(const float4*)&A[(size_t)(m0 + ia) * 256 + k0 + qa * 4 + 16];
        As[qa * 4 + 0][ia] = a0.x; As[qa * 4 + 1][ia] = a0.y;
        As[qa * 4 + 2][ia] = a0.z; As[qa * 4 + 3][ia] = a0.w;
        As[qa * 4 + 16][ia] = a1.x; As[qa * 4 + 17][ia] = a1.y;
        As[qa * 4 + 18][ia] = a1.z; As[qa * 4 + 19][ia] = a1.w;
#pragma unroll
        for (int r = 0; r < 8; ++r) {
            const int qd = qb + r * 8;
            *(float4*)&Bs[kb][qd * 4] =
                *(const float4*)&w1[(size_t)(k0 + kb) * 512 + n0 + qd * 4];
        }
        __syncthreads();
#pragma unroll 8
        for (int kk = 0; kk < 32; ++kk) {
            float4 av = *(const float4*)&As[kk][ty * 4];
            float4 b0 = *(const float4*)&Bs[kk][tx * 4];
            float4 b1_ = *(const float4*)&Bs[kk][64 + tx * 4];
            float4 b2 = *(const float4*)&Bs[kk][128 + tx * 4];
            float4 b3 = *(const float4*)&Bs[kk][192 + tx * 4];
            fma64(acc, av, b0, b1_, b2, b3);
        }
        __syncthreads();
    }
#pragma unroll
    for (int cc = 0; cc < 4; ++cc) {
        float4 bias = *(const float4*)&b1[n0 + cc * 64 + tx * 4];
#pragma unroll
        for (int ri = 0; ri < 4; ++ri) {
            ushort4 sv;
            sv.x = f2bf(gelu_f(acc[ri][cc * 4 + 0] + bias.x));
            sv.y = f2bf(gelu_f(acc[ri][cc * 4 + 1] + bias.y));
            sv.z = f2bf(gelu_f(acc[ri][cc * 4 + 2] + bias.z));
            sv.w = f2bf(gelu_f(acc[ri][cc * 4 + 3] + bias.w));
            *(ushort4*)&mid[(size_t)(m0 + ty * 4 + ri) * 512 + n0 + cc * 64 + tx * 4] = sv;
        }
    }
}

// --------------- K5: MLP GEMM2 + residual + NCHW transpose -----------------
// grid 1024, block 256.  M-tile 64, N=256 full, K=512.  A (mid) is bf16.
__global__ __launch_bounds__(256, 2)
void k5_mlp2(const unsigned short* __restrict__ A, const float* __restrict__ w2,
             const float* __restrict__ b2, const float* __restrict__ xt2,
             float* __restrict__ out) {
    __shared__ float smem[16640];                 // Ct[64][260] = 16640 floats
    float (*As)[68] = (float(*)[68])smem;         // 32*68  = 2176
    float (*Bs)[260] = (float(*)[260])(smem + 2176);  // 32*260 = 8320
    const int tid = threadIdx.x;
    const int m0 = blockIdx.x * 64;
    const int ty = tid >> 4, tx = tid & 15;
    const int ia = tid >> 2, qa = tid & 3;
    const int kb = tid >> 3, qb = tid & 7;

    float acc[4][16];
#pragma unroll
    for (int i = 0; i < 4; ++i)
#pragma unroll
        for (int j = 0; j < 16; ++j) acc[i][j] = 0.f;

    for (int kt = 0; kt < 16; ++kt) {
        const int k0 = kt * 32;
        // A tile: 8 bf16 per thread, rows=ia, k = k0 + qa*8 .. +7
        const uint4 u = *(const uint4*)&A[(size_t)(m0 + ia) * 512 + k0 + qa * 8];
        As[qa * 8 + 0][ia] = __uint_as_float(u.x << 16);
        As[qa * 8 + 1][ia] = __uint_as_float(u.x & 0xffff0000u);
        As[qa * 8 + 2][ia] = __uint_as_float(u.y << 16);
        As[qa * 8 + 3][ia] = __uint_as_float(u.y & 0xffff0000u);
        As[qa * 8 + 4][ia] = __uint_as_float(u.z << 16);
        As[qa * 8 + 5][ia] = __uint_as_float(u.z & 0xffff0000u);
        As[qa * 8 + 6][ia] = __uint_as_float(u.w << 16);
        As[qa * 8 + 7][ia] = __uint_as_float(u.w & 0xffff0000u);
#pragma unroll
        for (int r = 0; r < 8; ++r) {
            const int qd = qb + r * 8;
            *(float4*)&Bs[kb][qd * 4] =
                *(const float4*)&w2[(size_t)(k0 + kb) * 256 + qd * 4];
        }
        __syncthreads();
#pragma unroll 8
        for (int kk = 0; kk < 32; ++kk) {
            float4 av = *(const float4*)&As[kk][ty * 4];
            float4 b0 = *(const float4*)&Bs[kk][tx * 4];
            float4 b1_ = *(const float4*)&Bs[kk][64 + tx * 4];
            float4 b2_ = *(const float4*)&Bs[kk][128 + tx * 4];
            float4 b3 = *(const float4*)&Bs[kk][192 + tx * 4];
            fma64(acc, av, b0, b1_, b2_, b3);
        }
        __syncthreads();
    }
    // bias + residual, stage to Ct
#pragma unroll
    for (int cc = 0; cc < 4; ++cc) {
        float4 bias = *(const float4*)&b2[cc * 64 + tx * 4];
#pragma unroll
        for (int ri = 0; ri < 4; ++ri) {
            float4 xv = *(const float4*)&xt2[(size_t)(m0 + ty * 4 + ri) * 256 + cc * 64 + tx * 4];
            float4 v;
            v.x = acc[ri][cc * 4 + 0] + bias.x + xv.x;
            v.y = acc[ri][cc * 4 + 1] + bias.y + xv.y;
            v.z = acc[ri][cc * 4 + 2] + bias.z + xv.z;
            v.w = acc[ri][cc * 4 + 3] + bias.w + xv.w;
            *(float4*)&smem[(ty * 4 + ri) * 260 + cc * 64 + tx * 4] = v;
        }
    }
    __syncthreads();
    // transposed readout: out[b][c][s], 64 consecutive tokens per float4
    const int bb_ = m0 >> 12;
    const int s0 = m0 & 4095;
#pragma unroll
    for (int it = 0; it < 16; ++it) {
        const int cch = (tid >> 4) + it * 16;
        const int tq = tid & 15;
        float4 v;
        v.x = smem[(tq * 4 + 0) * 260 + cch];
        v.y = smem[(tq * 4 + 1) * 260 + cch];
        v.z = smem[(tq * 4 + 2) * 260 + cch];
        v.w = smem[(tq * 4 + 3) * 260 + cch];
        *(float4*)&out[(size_t)bb_ * 1048576 + (size_t)cch * 4096 + s0 + tq * 4] = v;
    }
}

// ---------------------------------------------------------------------------
extern "C" void kernel_launch(void* const* d_in, const int* in_sizes, int n_in,
                              void* d_out, int out_size, void* d_ws, size_t ws_size,
                              hipStream_t stream) {
    const float* x      = (const float*)d_in[0];
    const float* t      = (const float*)d_in[1];
    const float* skip   = (const float*)d_in[2];
    const float* z      = (const float*)d_in[3];
    const float* norm   = (const float*)d_in[4];
    const float* skip_w = (const float*)d_in[5];
    const float* skip_b = (const float*)d_in[6];
    const float* ln1_g  = (const float*)d_in[7];
    const float* ln1_b  = (const float*)d_in[8];
    const float* ln2_g  = (const float*)d_in[9];
    const float* ln2_b  = (const float*)d_in[10];
    const float* tm1_w  = (const float*)d_in[11];
    const float* tm1_b  = (const float*)d_in[12];
    const float* tm2_w  = (const float*)d_in[13];
    const float* tm2_b  = (const float*)d_in[14];
    const float* zm1_w1 = (const float*)d_in[15];
    const float* zm1_b1 = (const float*)d_in[16];
    const float* zm1_w2 = (const float*)d_in[17];
    const float* zm1_b2 = (const float*)d_in[18];
    const float* zm2_w1 = (const float*)d_in[19];
    const float* zm2_b1 = (const float*)d_in[20];
    const float* zm2_w2 = (const float*)d_in[21];
    const float* zm2_b2 = (const float*)d_in[22];
    const float* conv_k = (const float*)d_in[23];
    const float* mlp_w1 = (const float*)d_in[24];
    const float* mlp_b1 = (const float*)d_in[25];
    const float* mlp_w2 = (const float*)d_in[26];
    const float* mlp_b2 = (const float*)d_in[27];

    char* wsb = (char*)d_ws;
    float* xt            = (float*)wsb;                        // [0, 64Mi)  xt -> xt2 (in place)
    float* hf            = (float*)(wsb + REG_BYTES);          // [64,128Mi) hf -> hmod
    unsigned short* mid  = (unsigned short*)(wsb + 2 * REG_BYTES); // [128,192Mi) bf16 [M,512]
    float* vecs          = (float*)(wsb + 3 * REG_BYTES);      // +96KiB
    float* hmod = hf;

    k0_modvecs<<<dim3(6, 16), 256, 0, stream>>>(t, z, tm1_w, tm1_b, tm2_w, tm2_b,
                                                zm1_w1, zm1_b1, zm1_w2, zm1_b2,
                                                zm2_w1, zm2_b1, zm2_w2, zm2_b2, vecs);
    k1_skipgemm<<<1024, 256, 0, stream>>>(x, skip, skip_w, skip_b, ln1_g, ln1_b,
                                          vecs, xt, hf);
    k2_conv<<<4096, 256, 0, stream>>>(hf, xt, conv_k, norm);   // xt -> xt2 in place
    k3_mod2<<<16384, 256, 0, stream>>>(xt, ln2_g, ln2_b, vecs, hmod);
    k4_mlp1<<<dim3(1024, 2), 256, 0, stream>>>(hmod, mlp_w1, mlp_b1, mid);
    k5_mlp2<<<1024, 256, 0, stream>>>(mid, mlp_w2, mlp_b2, xt, (float*)d_out);
}

// Round 3
// 538.174 us; speedup vs baseline: 1.7922x; 1.7922x over previous
//
#include <hip/hip_runtime.h>

// ---------------------------------------------------------------------------
// SparseConvResBlock v3: bf16-MFMA GEMMs.
//   B=16, C=256, H=W=64 (M=65536 tokens), SKIP=256, TE=1024, ZD=256, K=7.
//
// Graph:
//   k0a  wtrans  : skip_w/mlp_w1/mlp_w2 fp32 -> [n][k] bf16 (Bt)
//   k0   modvecs : t/z FiLM vectors -> vecs[6][16][256] fp32
//   g1   skipgemm: MFMA [M,512]@Bt_skip + bias -> xt fp32
//   mod1         : LN1+FiLM(xt) -> hf bf16
//   k2   conv    : 7x7 dw(hf)/norm + xt -> xt (in place) ; NCHW copy -> d_out
//   mod2         : LN2+FiLM(xt2) -> hmod bf16 (hf region)
//   g4   mlp1    : MFMA gelu(hmod@Bt_w1+b1) -> mid bf16
//   g5   mlp2    : MFMA (swapped: D[ch][tok]) mid@Bt_w2+b2 += d_out
//
// ws (bytes): [0,64Mi) xt fp32 | [64,96Mi) hf/hmod bf16 | [96,160Mi) mid bf16
//             [160Mi..) Bt_skip(256K) Bt_w1(256K) Bt_w2(256K) vecs(96K)
// ---------------------------------------------------------------------------

typedef unsigned short u16;
typedef __attribute__((ext_vector_type(8))) short bf16x8;
typedef __attribute__((ext_vector_type(4))) float f32x4;

#define MFMA16(a, b, c) __builtin_amdgcn_mfma_f32_16x16x32_bf16((a), (b), (c), 0, 0, 0)

// LDS tile row pitch (elements): 40 (=80B) keeps ds_*_b128 16B-aligned and
// spreads rows over 8 bank-groups (2-way max aliasing = free per m136).
#define WPITCH 40

__device__ __forceinline__ float gelu_f(float x) {
    return 0.5f * x * (1.0f + erff(x * 0.70710678118654752f));
}
__device__ __forceinline__ u16 f2bf(float f) {
    unsigned int u = __float_as_uint(f);
    unsigned int r = (u + 0x7FFFu + ((u >> 16) & 1u)) >> 16;
    return (u16)r;
}
__device__ __forceinline__ float bf2f(u16 h) {
    return __uint_as_float((unsigned int)h << 16);
}

// ------------------------ k0a: weight transpose to bf16 --------------------
// 96 blocks x 256: [0,32) skip_w 512x256 -> [256][512]; [32,64) mlp_w1
// 256x512 -> [512][256]; [64,96) mlp_w2 512x256 -> [256][512].
__global__ void k0a_wtrans(const float* __restrict__ skip_w,
                           const float* __restrict__ mlp_w1,
                           const float* __restrict__ mlp_w2,
                           u16* __restrict__ bt_skip, u16* __restrict__ bt_w1,
                           u16* __restrict__ bt_w2) {
    __shared__ float tile[64][68];
    const int bid = blockIdx.x, tid = threadIdx.x;
    const float* src;
    u16* dst;
    int K, N, kt, nt;
    if (bid < 32) { src = skip_w; dst = bt_skip; K = 512; N = 256; kt = bid >> 2; nt = bid & 3; }
    else if (bid < 64) { int b2 = bid - 32; src = mlp_w1; dst = bt_w1; K = 256; N = 512; kt = b2 >> 3; nt = b2 & 7; }
    else { int b3 = bid - 64; src = mlp_w2; dst = bt_w2; K = 512; N = 256; kt = b3 >> 2; nt = b3 & 3; }
    const int k0 = kt * 64, n0 = nt * 64;
#pragma unroll
    for (int it = 0; it < 4; ++it) {
        const int kr = it * 16 + (tid >> 4);
        float4 v = *(const float4*)&src[(size_t)(k0 + kr) * N + n0 + (tid & 15) * 4];
        *(float4*)&tile[kr][(tid & 15) * 4] = v;
    }
    __syncthreads();
#pragma unroll
    for (int it = 0; it < 4; ++it) {
        const int nr = it * 16 + (tid >> 4);
        const int kq = tid & 15;
        ushort4 o;
        o.x = f2bf(tile[kq * 4 + 0][nr]);
        o.y = f2bf(tile[kq * 4 + 1][nr]);
        o.z = f2bf(tile[kq * 4 + 2][nr]);
        o.w = f2bf(tile[kq * 4 + 3][nr]);
        *(ushort4*)&dst[(size_t)(n0 + nr) * K + k0 + kq * 4] = o;
    }
}

// --------------------------- k0: FiLM vectors ------------------------------
__global__ void k0_modvecs(const float* __restrict__ t, const float* __restrict__ z,
                           const float* __restrict__ tm1_w, const float* __restrict__ tm1_b,
                           const float* __restrict__ tm2_w, const float* __restrict__ tm2_b,
                           const float* __restrict__ zm1_w1, const float* __restrict__ zm1_b1,
                           const float* __restrict__ zm1_w2, const float* __restrict__ zm1_b2,
                           const float* __restrict__ zm2_w1, const float* __restrict__ zm2_b1,
                           const float* __restrict__ zm2_w2, const float* __restrict__ zm2_b2,
                           float* __restrict__ vecs) {
    const int unit = blockIdx.x;
    const int b = blockIdx.y;
    const int tid = threadIdx.x;
    __shared__ float sb[1024];
    if (unit < 4) {
        const float* tw = (unit < 2) ? tm1_w : tm2_w;
        const float* tb = (unit < 2) ? tm1_b : tm2_b;
        for (int i = tid; i < 1024; i += 256) sb[i] = gelu_f(t[b * 1024 + i]);
        __syncthreads();
        const int half = unit & 1;
        const int n = half * 256 + tid;
        float acc = tb[n];
#pragma unroll 8
        for (int k = 0; k < 1024; ++k) acc = fmaf(sb[k], tw[k * 512 + n], acc);
        const int slot = (unit < 2) ? half : (2 + half);
        vecs[(slot * 16 + b) * 256 + tid] = acc;
    } else {
        const float* w1 = (unit == 4) ? zm1_w1 : zm2_w1;
        const float* b1 = (unit == 4) ? zm1_b1 : zm2_b1;
        const float* w2 = (unit == 4) ? zm1_w2 : zm2_w2;
        const float* b2 = (unit == 4) ? zm1_b2 : zm2_b2;
        sb[tid] = z[b * 256 + tid];
        __syncthreads();
        float acc = b1[tid];
#pragma unroll 8
        for (int k = 0; k < 256; ++k) acc = fmaf(sb[k], w1[k * 256 + tid], acc);
        sb[256 + tid] = gelu_f(acc);
        __syncthreads();
        float acc2 = b2[tid];
#pragma unroll 8
        for (int k = 0; k < 256; ++k) acc2 = fmaf(sb[256 + k], w2[k * 256 + tid], acc2);
        vecs[((unit) * 16 + b) * 256 + tid] = acc2;
    }
}

// -------------------- g1: skip_linear GEMM (MFMA) + bias -------------------
// grid 1024 (=M/64), block 256 (4 waves).  Tile: 64 tok x 256 ch, BK=32.
// Wave w: cols w*64..+63.  A-op = tokens (LDS-transposed from NCHW x/skip),
// B-op = Bt_skip [256][512] bf16.
__global__ __launch_bounds__(256)
void g1_skipgemm(const float* __restrict__ x, const float* __restrict__ skip,
                 const u16* __restrict__ btw, const float* __restrict__ skip_b,
                 float* __restrict__ xt) {
    __shared__ u16 Ws[256 * WPITCH];
    __shared__ u16 Xs[64 * WPITCH];
    const int tid = threadIdx.x;
    const int lane = tid & 63, wave = tid >> 6;
    const int m0 = blockIdx.x * 64;
    const int b = m0 >> 12, s0 = m0 & 4095;
    const float* xb = x + (size_t)b * 1048576 + s0;
    const float* sb_ = skip + (size_t)b * 1048576 + s0;

    f32x4 acc[4][4] = {};
    for (int kt = 0; kt < 16; ++kt) {
        const int k0 = kt * 32;
#pragma unroll
        for (int c = 0; c < 4; ++c) {
            const int id = c * 256 + tid;
            const int r = id >> 2, s = id & 3;
            uint4 v = *(const uint4*)&btw[(size_t)r * 512 + k0 + s * 8];
            *(uint4*)&Ws[r * WPITCH + s * 8] = v;
        }
        {   // transpose-stage 8 k-rows per wave: lane = token
            const int kg = k0 + wave * 8;
            float v[8];
#pragma unroll
            for (int q = 0; q < 8; ++q) {
                const int ch = kg + q;
                const float* p = (ch < 256) ? (xb + (size_t)ch * 4096)
                                            : (sb_ + (size_t)(ch - 256) * 4096);
                v[q] = p[lane];
            }
            uint4 pk;
            pk.x = f2bf(v[0]) | ((unsigned)f2bf(v[1]) << 16);
            pk.y = f2bf(v[2]) | ((unsigned)f2bf(v[3]) << 16);
            pk.z = f2bf(v[4]) | ((unsigned)f2bf(v[5]) << 16);
            pk.w = f2bf(v[6]) | ((unsigned)f2bf(v[7]) << 16);
            *(uint4*)&Xs[lane * WPITCH + wave * 8] = pk;
        }
        __syncthreads();
        bf16x8 xa[4], wb[4];
#pragma unroll
        for (int f = 0; f < 4; ++f)
            xa[f] = *(const bf16x8*)&Xs[(f * 16 + (lane & 15)) * WPITCH + (lane >> 4) * 8];
#pragma unroll
        for (int f = 0; f < 4; ++f)
            wb[f] = *(const bf16x8*)&Ws[(wave * 64 + f * 16 + (lane & 15)) * WPITCH + (lane >> 4) * 8];
#pragma unroll
        for (int i = 0; i < 4; ++i)
#pragma unroll
            for (int j = 0; j < 4; ++j)
                acc[i][j] = MFMA16(xa[i], wb[j], acc[i][j]);
        __syncthreads();
    }
#pragma unroll
    for (int j = 0; j < 4; ++j) {
        const int col = wave * 64 + j * 16 + (lane & 15);
        const float bias = skip_b[col];
#pragma unroll
        for (int i = 0; i < 4; ++i) {
            const int row = m0 + i * 16 + ((lane >> 4) << 2);
#pragma unroll
            for (int r = 0; r < 4; ++r)
                xt[(size_t)(row + r) * 256 + col] = acc[i][j][r] + bias;
        }
    }
}

// ---------------------- k_mod: LN + FiLM -> bf16 ---------------------------
// grid 16384, block 256 (wave per token).
__global__ void k_mod(const float* __restrict__ src,
                      const float* __restrict__ ln_g, const float* __restrict__ ln_b,
                      const float* __restrict__ vecs, const int sS, const int sB,
                      const int sZ, u16* __restrict__ dst) {
    const int tid = threadIdx.x;
    const int wid = tid >> 6, lane = tid & 63;
    const int token = blockIdx.x * 4 + wid;
    const int b = token >> 12;
    const float4 v = *(const float4*)&src[(size_t)token * 256 + lane * 4];
    float s1 = v.x + v.y + v.z + v.w;
    float s2 = v.x * v.x + v.y * v.y + v.z * v.z + v.w * v.w;
#pragma unroll
    for (int m = 1; m < 64; m <<= 1) {
        s1 += __shfl_xor(s1, m);
        s2 += __shfl_xor(s2, m);
    }
    const float mean = s1 * (1.f / 256.f);
    const float var = s2 * (1.f / 256.f) - mean * mean;
    const float rstd = rsqrtf(var + 1e-5f);
    const int col = lane * 4;
    float4 g = *(const float4*)&ln_g[col];
    float4 bb = *(const float4*)&ln_b[col];
    float4 ts = *(const float4*)&vecs[(sS * 16 + b) * 256 + col];
    float4 th = *(const float4*)&vecs[(sB * 16 + b) * 256 + col];
    float4 zz = *(const float4*)&vecs[(sZ * 16 + b) * 256 + col];
    float h0 = (v.x - mean) * rstd * g.x + bb.x;
    float h1 = (v.y - mean) * rstd * g.y + bb.y;
    float h2 = (v.z - mean) * rstd * g.z + bb.z;
    float h3 = (v.w - mean) * rstd * g.w + bb.w;
    h0 = (h0 * (1.f + ts.x) + th.x) * (1.f + zz.x);
    h1 = (h1 * (1.f + ts.y) + th.y) * (1.f + zz.y);
    h2 = (h2 * (1.f + ts.z) + th.z) * (1.f + zz.z);
    h3 = (h3 * (1.f + ts.w) + th.w) * (1.f + zz.w);
    ushort4 o;
    o.x = f2bf(h0); o.y = f2bf(h1); o.z = f2bf(h2); o.w = f2bf(h3);
    *(ushort4*)&dst[(size_t)token * 256 + col] = o;
}

// -------------------- k2: depthwise 7x7 conv + residual --------------------
// grid 4096 = b(16) x tile(16) x cg(16).  block 256.  hf is bf16.
// Writes conv+residual IN PLACE over xtio (token-major) AND the same values
// NCHW-layout into outn (= d_out), which g5 later accumulates into.
__global__ __launch_bounds__(256, 2)
void k2_conv(const u16* __restrict__ hf, float* __restrict__ xtio,
             const float* __restrict__ conv_k, const float* __restrict__ norm,
             float* __restrict__ outn) {
    __shared__ float in_t[16 * 616];   // [c][yy 22][xx stride 28]
    __shared__ float wk[16 * 49];
    const int bid = blockIdx.x;
    const int cg = bid & 15;
    const int tile = (bid >> 4) & 15;
    const int b = bid >> 8;
    const int y0 = (tile >> 2) * 16, x0 = (tile & 3) * 16;
    const int c0 = cg * 16;
    const int tid = threadIdx.x;

    for (int it = 0; it < 8; ++it) {
        const int idx = it * 256 + tid;
        if (idx < 1936) {
            const int c4 = idx & 3, px = idx >> 2;
            const int yy = px / 22, xx = px - yy * 22;
            const int gy = y0 + yy - 3, gx = x0 + xx - 3;
            float4 v = make_float4(0.f, 0.f, 0.f, 0.f);
            if ((unsigned)gy < 64u && (unsigned)gx < 64u) {
                const ushort4 hv = *(const ushort4*)&hf[((size_t)(b * 4096 + gy * 64 + gx)) * 256 + c0 + c4 * 4];
                v = make_float4(bf2f(hv.x), bf2f(hv.y), bf2f(hv.z), bf2f(hv.w));
            }
            const int base = (c4 * 4) * 616 + yy * 28 + xx;
            in_t[base] = v.x; in_t[base + 616] = v.y;
            in_t[base + 1232] = v.z; in_t[base + 1848] = v.w;
        }
    }
    for (int idx = tid; idx < 784; idx += 256) wk[idx] = conv_k[c0 * 49 + idx];
    __syncthreads();

    const int c = tid >> 4, yy = tid & 15;
    float w[49];
#pragma unroll
    for (int i = 0; i < 49; ++i) w[i] = wk[c * 49 + i];
    float acc[16];
#pragma unroll
    for (int i = 0; i < 16; ++i) acc[i] = 0.f;
    const float* rowbase = &in_t[c * 616];
#pragma unroll
    for (int ky = 0; ky < 7; ++ky) {
        float r[24];
#pragma unroll
        for (int q = 0; q < 6; ++q)
            *(float4*)&r[q * 4] = *(const float4*)&rowbase[(yy + ky) * 28 + q * 4];
#pragma unroll
        for (int kx = 0; kx < 7; ++kx) {
            const float wv = w[ky * 7 + kx];
#pragma unroll
            for (int xo = 0; xo < 16; ++xo)
                acc[xo] = fmaf(wv, r[xo + kx], acc[xo]);
        }
    }
    float nr[16];
#pragma unroll
    for (int q = 0; q < 4; ++q)
        *(float4*)&nr[q * 4] = *(const float4*)&norm[(y0 + yy) * 64 + x0 + q * 4];
#pragma unroll
    for (int xo = 0; xo < 16; ++xo) acc[xo] = acc[xo] / nr[xo];

    __syncthreads();
    float* out_t = in_t;               // [px 256][17]
#pragma unroll
    for (int xo = 0; xo < 16; ++xo)
        out_t[(yy * 16 + xo) * 17 + c] = acc[xo];
    __syncthreads();
    // NHWC: add residual (token-major), write back both global and LDS
    for (int it = 0; it < 4; ++it) {
        const int idx = it * 256 + tid;
        const int c4 = idx & 3, px = idx >> 2;
        const int lb = px * 17 + c4 * 4;
        float4 v = make_float4(out_t[lb], out_t[lb + 1], out_t[lb + 2], out_t[lb + 3]);
        const size_t g = ((size_t)(b * 4096 + (y0 + (px >> 4)) * 64 + x0 + (px & 15))) * 256
                         + c0 + c4 * 4;
        float4 xv = *(const float4*)&xtio[g];
        v.x += xv.x; v.y += xv.y; v.z += xv.z; v.w += xv.w;
        *(float4*)&xtio[g] = v;
        out_t[lb] = v.x; out_t[lb + 1] = v.y; out_t[lb + 2] = v.z; out_t[lb + 3] = v.w;
    }
    __syncthreads();
    // NCHW copy of xt2 into d_out (g5 accumulates MLP output on top)
    {
        float vv[16];
#pragma unroll
        for (int xx = 0; xx < 16; ++xx) vv[xx] = out_t[(yy * 16 + xx) * 17 + c];
        float4* dst = (float4*)&outn[((size_t)(b * 256 + c0 + c)) * 4096 + (y0 + yy) * 64 + x0];
#pragma unroll
        for (int q = 0; q < 4; ++q)
            dst[q] = make_float4(vv[q * 4], vv[q * 4 + 1], vv[q * 4 + 2], vv[q * 4 + 3]);
    }
}

// ------------------------ g4: MLP GEMM1 (MFMA) + gelu ----------------------
// grid (1024, 2), block 256.  Tile 64 tok x 256 ch (of 512), BK=32, K=256.
__global__ __launch_bounds__(256)
void g4_mlp1(const u16* __restrict__ A, const u16* __restrict__ btw,
             const float* __restrict__ b1, u16* __restrict__ mid) {
    __shared__ u16 Ws[256 * WPITCH];
    __shared__ u16 Xs[64 * WPITCH];
    const int tid = threadIdx.x;
    const int lane = tid & 63, wave = tid >> 6;
    const int m0 = blockIdx.x * 64;
    const int n0 = blockIdx.y * 256;
    const int rA = tid >> 2, sA = tid & 3;
    f32x4 acc[4][4] = {};
    for (int kt = 0; kt < 8; ++kt) {
        const int k0 = kt * 32;
#pragma unroll
        for (int c = 0; c < 4; ++c) {
            const int id = c * 256 + tid;
            const int r = id >> 2, s = id & 3;
            uint4 v = *(const uint4*)&btw[(size_t)(n0 + r) * 256 + k0 + s * 8];
            *(uint4*)&Ws[r * WPITCH + s * 8] = v;
        }
        {
            uint4 v = *(const uint4*)&A[(size_t)(m0 + rA) * 256 + k0 + sA * 8];
            *(uint4*)&Xs[rA * WPITCH + sA * 8] = v;
        }
        __syncthreads();
        bf16x8 xa[4], wb[4];
#pragma unroll
        for (int f = 0; f < 4; ++f)
            xa[f] = *(const bf16x8*)&Xs[(f * 16 + (lane & 15)) * WPITCH + (lane >> 4) * 8];
#pragma unroll
        for (int f = 0; f < 4; ++f)
            wb[f] = *(const bf16x8*)&Ws[(wave * 64 + f * 16 + (lane & 15)) * WPITCH + (lane >> 4) * 8];
#pragma unroll
        for (int i = 0; i < 4; ++i)
#pragma unroll
            for (int j = 0; j < 4; ++j)
                acc[i][j] = MFMA16(xa[i], wb[j], acc[i][j]);
        __syncthreads();
    }
#pragma unroll
    for (int j = 0; j < 4; ++j) {
        const int col = n0 + wave * 64 + j * 16 + (lane & 15);
        const float bias = b1[col];
#pragma unroll
        for (int i = 0; i < 4; ++i) {
            const int row = m0 + i * 16 + ((lane >> 4) << 2);
#pragma unroll
            for (int r = 0; r < 4; ++r)
                mid[(size_t)(row + r) * 512 + col] = f2bf(gelu_f(acc[i][j][r] + bias));
        }
    }
}

// ------------- g5: MLP GEMM2 (MFMA, swapped) + bias + accumulate -----------
// grid 1024, block 256.  D[ch][tok]: A-op = Bt_w2 [256][512], B-op = mid.
// out (d_out) already holds xt2 in NCHW from k2_conv; accumulate into it.
__global__ __launch_bounds__(256)
void g5_mlp2(const u16* __restrict__ midp, const u16* __restrict__ btw,
             const float* __restrict__ b2, float* out) {
    __shared__ u16 Ws[256 * WPITCH];
    __shared__ u16 Xs[64 * WPITCH];
    const int tid = threadIdx.x;
    const int lane = tid & 63, wave = tid >> 6;
    const int m0 = blockIdx.x * 64;
    const int b = m0 >> 12, s0 = m0 & 4095;
    const int rA = tid >> 2, sA = tid & 3;
    f32x4 acc[4][4] = {};
    for (int kt = 0; kt < 16; ++kt) {
        const int k0 = kt * 32;
#pragma unroll
        for (int c = 0; c < 4; ++c) {
            const int id = c * 256 + tid;
            const int r = id >> 2, s = id & 3;
            uint4 v = *(const uint4*)&btw[(size_t)r * 512 + k0 + s * 8];
            *(uint4*)&Ws[r * WPITCH + s * 8] = v;
        }
        {
            uint4 v = *(const uint4*)&midp[(size_t)(m0 + rA) * 512 + k0 + sA * 8];
            *(uint4*)&Xs[rA * WPITCH + sA * 8] = v;
        }
        __syncthreads();
        bf16x8 xa[4], wb[4];
#pragma unroll
        for (int f = 0; f < 4; ++f)
            xa[f] = *(const bf16x8*)&Xs[(f * 16 + (lane & 15)) * WPITCH + (lane >> 4) * 8];
#pragma unroll
        for (int f = 0; f < 4; ++f)
            wb[f] = *(const bf16x8*)&Ws[(wave * 64 + f * 16 + (lane & 15)) * WPITCH + (lane >> 4) * 8];
        // swapped: D rows = weight rows (channels), D cols = tokens
#pragma unroll
        for (int i = 0; i < 4; ++i)
#pragma unroll
            for (int j = 0; j < 4; ++j)
                acc[i][j] = MFMA16(wb[i], xa[j], acc[i][j]);
        __syncthreads();
    }
#pragma unroll
    for (int i = 0; i < 4; ++i) {
#pragma unroll
        for (int r = 0; r < 4; ++r) {
            const int ch = wave * 64 + i * 16 + ((lane >> 4) << 2) + r;
            const float bias = b2[ch];
            float* po = out + (size_t)b * 1048576 + (size_t)ch * 4096 + s0;
#pragma unroll
            for (int j = 0; j < 4; ++j) {
                const int tok = j * 16 + (lane & 15);
                po[tok] = po[tok] + acc[i][j][r] + bias;
            }
        }
    }
}

// ---------------------------------------------------------------------------
extern "C" void kernel_launch(void* const* d_in, const int* in_sizes, int n_in,
                              void* d_out, int out_size, void* d_ws, size_t ws_size,
                              hipStream_t stream) {
    const float* x      = (const float*)d_in[0];
    const float* t      = (const float*)d_in[1];
    const float* skip   = (const float*)d_in[2];
    const float* z      = (const float*)d_in[3];
    const float* norm   = (const float*)d_in[4];
    const float* skip_w = (const float*)d_in[5];
    const float* skip_b = (const float*)d_in[6];
    const float* ln1_g  = (const float*)d_in[7];
    const float* ln1_b  = (const float*)d_in[8];
    const float* ln2_g  = (const float*)d_in[9];
    const float* ln2_b  = (const float*)d_in[10];
    const float* tm1_w  = (const float*)d_in[11];
    const float* tm1_b  = (const float*)d_in[12];
    const float* tm2_w  = (const float*)d_in[13];
    const float* tm2_b  = (const float*)d_in[14];
    const float* zm1_w1 = (const float*)d_in[15];
    const float* zm1_b1 = (const float*)d_in[16];
    const float* zm1_w2 = (const float*)d_in[17];
    const float* zm1_b2 = (const float*)d_in[18];
    const float* zm2_w1 = (const float*)d_in[19];
    const float* zm2_b1 = (const float*)d_in[20];
    const float* zm2_w2 = (const float*)d_in[21];
    const float* zm2_b2 = (const float*)d_in[22];
    const float* conv_k = (const float*)d_in[23];
    const float* mlp_w1 = (const float*)d_in[24];
    const float* mlp_b1 = (const float*)d_in[25];
    const float* mlp_w2 = (const float*)d_in[26];
    const float* mlp_b2 = (const float*)d_in[27];

    char* wsb = (char*)d_ws;
    float* xt   = (float*)wsb;                                   // 64 MiB fp32, conv in-place
    u16*  hf    = (u16*)(wsb + ((size_t)64 << 20));              // 32 MiB bf16 (hf -> hmod)
    u16*  mid   = (u16*)(wsb + ((size_t)96 << 20));              // 64 MiB bf16
    u16*  bts   = (u16*)(wsb + ((size_t)160 << 20));             // 256 KiB
    u16*  btw1  = bts + 131072;                                  // 256 KiB
    u16*  btw2  = btw1 + 131072;                                 // 256 KiB
    float* vecs = (float*)(btw2 + 131072);                       // 96 KiB
    float* outp = (float*)d_out;

    k0a_wtrans<<<96, 256, 0, stream>>>(skip_w, mlp_w1, mlp_w2, bts, btw1, btw2);
    k0_modvecs<<<dim3(6, 16), 256, 0, stream>>>(t, z, tm1_w, tm1_b, tm2_w, tm2_b,
                                                zm1_w1, zm1_b1, zm1_w2, zm1_b2,
                                                zm2_w1, zm2_b1, zm2_w2, zm2_b2, vecs);
    g1_skipgemm<<<1024, 256, 0, stream>>>(x, skip, bts, skip_b, xt);
    k_mod<<<16384, 256, 0, stream>>>(xt, ln1_g, ln1_b, vecs, 0, 1, 4, hf);
    k2_conv<<<4096, 256, 0, stream>>>(hf, xt, conv_k, norm, outp);
    k_mod<<<16384, 256, 0, stream>>>(xt, ln2_g, ln2_b, vecs, 2, 3, 5, hf);   // hmod
    g4_mlp1<<<dim3(1024, 2), 256, 0, stream>>>(hf, btw1, mlp_b1, mid);
    g5_mlp2<<<1024, 256, 0, stream>>>(mid, btw2, mlp_b2, outp);
}